// Round 5
// baseline (397.035 us; speedup 1.0000x reference)
//
#include <hip/hip_runtime.h>
#include <math.h>

#define MM 65536   // nodes
#define NN 65536   // edges
#define KTOP 64

// ---------------------------------------------------------------------------
// Kernel 1: G = Wq^T @ Wk   (512x512)
// ---------------------------------------------------------------------------
__global__ void k_gemm_G(const float* __restrict__ Wq, const float* __restrict__ Wk,
                         float* __restrict__ G)
{
    __shared__ float As[32][33];
    __shared__ float Bs[32][33];
    const int t  = threadIdx.x;
    const int tm = t >> 4, tn = t & 15;
    const int m0 = (blockIdx.x >> 4) * 32, n0 = (blockIdx.x & 15) * 32;
    float a00 = 0.f, a01 = 0.f, a10 = 0.f, a11 = 0.f;
    for (int d0 = 0; d0 < 512; d0 += 32) {
        for (int i = t; i < 1024; i += 256) {
            int r = i >> 5, c = i & 31;
            As[r][c] = Wq[(size_t)(d0 + r) * 512 + m0 + c];
            Bs[r][c] = Wk[(size_t)(d0 + r) * 512 + n0 + c];
        }
        __syncthreads();
        #pragma unroll 8
        for (int k = 0; k < 32; ++k) {
            float x0 = As[k][tm * 2], x1 = As[k][tm * 2 + 1];
            float y0 = Bs[k][tn * 2], y1 = Bs[k][tn * 2 + 1];
            a00 += x0 * y0; a01 += x0 * y1; a10 += x1 * y0; a11 += x1 * y1;
        }
        __syncthreads();
    }
    G[(size_t)(m0 + tm * 2 + 0) * 512 + n0 + tn * 2 + 0] = a00;
    G[(size_t)(m0 + tm * 2 + 0) * 512 + n0 + tn * 2 + 1] = a01;
    G[(size_t)(m0 + tm * 2 + 1) * 512 + n0 + tn * 2 + 0] = a10;
    G[(size_t)(m0 + tm * 2 + 1) * 512 + n0 + tn * 2 + 1] = a11;
}

// ---------------------------------------------------------------------------
// Kernel 2: per-batch vectors bL, bR, cB
// ---------------------------------------------------------------------------
__global__ void k_batch(const float* __restrict__ qs, const float* __restrict__ qr,
                        const float* __restrict__ G,
                        float* __restrict__ bL, float* __restrict__ bR, float* __restrict__ cB)
{
    const int e = blockIdx.x, t = threadIdx.x;
    __shared__ float qcat[256];
    __shared__ float whi[256];
    __shared__ float red[256];
    qcat[t] = (t < 128) ? qs[(size_t)e * 128 + t] : qr[(size_t)e * 128 + (t - 128)];
    __syncthreads();
    float w0 = 0.f, w1 = 0.f;
    for (int r = 0; r < 256; ++r) {
        float q = qcat[r];
        w0 += G[(size_t)t * 512 + 256 + r] * q;
        w1 += G[(size_t)(t + 256) * 512 + 256 + r] * q;
    }
    bL[(size_t)e * 256 + t] = w0;
    whi[t] = w1;
    float v = 0.f;
    for (int r = 0; r < 256; ++r)
        v += qcat[r] * G[(size_t)(256 + r) * 512 + t];
    bR[(size_t)e * 256 + t] = v;
    __syncthreads();
    red[t] = qcat[t] * whi[t];
    __syncthreads();
    for (int s = 128; s > 0; s >>= 1) {
        if (t < s) red[t] += red[t + s];
        __syncthreads();
    }
    if (t == 0) cB[e] = red[0];
}

// ---------------------------------------------------------------------------
// Kernel 3 v2.1: per-edge logits.  64 edges/block, 256 threads.
// Thread (p = t>>4, g = (t>>1)&7, kh = t&1):
//   4 edges (4p..4p+3) x 8 cols (g*8..+7 per 64-col tile) x k-half kh.
// FIX vs v2: bR epilogue term gated on kh==0 (was double-counted across kh).
// ---------------------------------------------------------------------------
#define FMAROW(J, AX) \
    acc[J][0] += AX * b0.x; acc[J][1] += AX * b0.y; \
    acc[J][2] += AX * b0.z; acc[J][3] += AX * b0.w; \
    acc[J][4] += AX * b1.x; acc[J][5] += AX * b1.y; \
    acc[J][6] += AX * b1.z; acc[J][7] += AX * b1.w;

__launch_bounds__(256, 2)
__global__ void k_edge(const float* __restrict__ vnr, const float* __restrict__ rel,
                       const int* __restrict__ edges, const float* __restrict__ G,
                       const float* __restrict__ bL, const float* __restrict__ bR,
                       const float* __restrict__ cB, float* __restrict__ logits)
{
    __shared__ __align__(16) float At[128][64];
    __shared__ __align__(16) float Bt[128][64];
    __shared__ __align__(16) float bLs[256];
    __shared__ __align__(16) float bRs[256];
    __shared__ int jL[64];

    const int t  = threadIdx.x;
    const int n0 = blockIdx.x * 64;
    const int eg = n0 >> 10;

    const int kh = t & 1;
    const int g  = (t >> 1) & 7;
    const int p  = t >> 4;
    const int e0 = p * 4;
    const int eS = t & 63, rep = t >> 6;
    const int kk2 = t >> 1, half = t & 1;

    // ---- initial global issues (all complete by the first barrier)
    if (t < 64) jL[t] = edges[(size_t)(n0 + t) * 8 + 7];
    bLs[t] = bL[(size_t)eg * 256 + t];
    bRs[t] = bR[(size_t)eg * 256 + t];

    float4 apre[8], gpre[8];
    {
        int segMine = edges[(size_t)(n0 + eS) * 8 + 6];
        const float* asrc = vnr + (size_t)segMine * 128 + rep * 32;
        #pragma unroll
        for (int w = 0; w < 8; ++w) apre[w] = *(const float4*)(asrc + w * 4);
        const float* gsrc = G + (size_t)kk2 * 512 + half * 32;
        #pragma unroll
        for (int w = 0; w < 8; ++w) gpre[w] = *(const float4*)(gsrc + w * 4);
    }
    __syncthreads();                       // jL/bLs/bRs visible, loads done

    double s[4] = {0.0, 0.0, 0.0, 0.0};

    for (int kt = 0; kt < 2; ++kt) {
        if (kt > 0) __syncthreads();       // all reads of previous At/Bt done
        // ---- stage At from apre
        #pragma unroll
        for (int w = 0; w < 8; ++w) {
            int k = rep * 32 + w * 4;
            At[k + 0][eS] = apre[w].x; At[k + 1][eS] = apre[w].y;
            At[k + 2][eS] = apre[w].z; At[k + 3][eS] = apre[w].w;
        }
        __syncthreads();                   // At visible
        if (kt == 0) {                     // prefetch A rows for kt=1
            const float* asrc = rel + (size_t)(n0 + eS) * 128 + rep * 32;
            #pragma unroll
            for (int w = 0; w < 8; ++w) apre[w] = *(const float4*)(asrc + w * 4);
        }
        // ---- bL partial: k = (t&15)*8 .. +7 for this thread's 4 edges
        {
            float la[4] = {0.f, 0.f, 0.f, 0.f};
            const int kb = (t & 15) * 8;
            #pragma unroll
            for (int i = 0; i < 8; ++i) {
                int k = kb + i;
                float bl = bLs[kt * 128 + k];
                float4 a = *(const float4*)&At[k][e0];
                la[0] += a.x * bl; la[1] += a.y * bl;
                la[2] += a.z * bl; la[3] += a.w * bl;
            }
            #pragma unroll
            for (int j = 0; j < 4; ++j) s[j] += (double)la[j];
        }

        for (int ct = 0; ct < 4; ++ct) {
            const int tt = kt * 4 + ct;
            if (ct > 0) __syncthreads();   // previous Bt fully consumed
            // ---- stage Bt from gpre (swizzled)
            {
                const int swz = ((kk2 & 7) << 3) ^ (((kk2 >> 6) & 1) << 2);
                #pragma unroll
                for (int w = 0; w < 8; ++w) {
                    int c  = half * 32 + w * 4;
                    *(float4*)&Bt[kk2][c ^ swz] = gpre[w];
                }
            }
            __syncthreads();               // Bt visible
            // ---- prefetch next G tile
            if (tt < 7) {
                const int ntt = tt + 1, nkt = ntt >> 2, nct = ntt & 3;
                const float* gsrc = G + (size_t)(nkt * 128 + kk2) * 512 + nct * 64 + half * 32;
                #pragma unroll
                for (int w = 0; w < 8; ++w) gpre[w] = *(const float4*)(gsrc + w * 4);
            }
            // ---- prefetch Rh rows for this ct's epilogue
            float4 rpre[8];
            #pragma unroll
            for (int j = 0; j < 4; ++j) {
                const float* rp = (ct < 2)
                    ? (vnr + (size_t)jL[e0 + j] * 128 + ct * 64 + g * 8)
                    : (rel + (size_t)(n0 + e0 + j) * 128 + (ct - 2) * 64 + g * 8);
                rpre[2 * j]     = *(const float4*)(rp);
                rpre[2 * j + 1] = *(const float4*)(rp + 4);
            }
            // ---- 64(e) x 64(c) x 64(k-half) FMA tile
            float acc[4][8] = {};
            const int cb0 = (g * 8) ^ (kh << 2);
            #pragma unroll 8
            for (int i = 0; i < 64; ++i) {
                const int kk = kh * 64 + i;
                float4 a  = *(const float4*)&At[kk][e0];
                const int cb = cb0 ^ ((i & 7) << 3);
                float4 b0 = *(const float4*)&Bt[kk][cb];
                float4 b1 = *(const float4*)&Bt[kk][cb ^ 4];
                FMAROW(0, a.x) FMAROW(1, a.y) FMAROW(2, a.z) FMAROW(3, a.w)
            }
            // ---- epilogue: dot with Rh (+ bR term ONCE: kt==0 AND kh==0)
            const int cbase = ct * 64 + g * 8;
            const bool doBR = (kt == 0) && (kh == 0);
            float4 br0, br1;
            if (doBR) {
                br0 = *(const float4*)&bRs[cbase];
                br1 = *(const float4*)&bRs[cbase + 4];
            }
            #pragma unroll
            for (int j = 0; j < 4; ++j) {
                float4 ra = rpre[2 * j], rb = rpre[2 * j + 1];
                float d = acc[j][0] * ra.x + acc[j][1] * ra.y + acc[j][2] * ra.z + acc[j][3] * ra.w
                        + acc[j][4] * rb.x + acc[j][5] * rb.y + acc[j][6] * rb.z + acc[j][7] * rb.w;
                if (doBR) {
                    d += ra.x * br0.x + ra.y * br0.y + ra.z * br0.z + ra.w * br0.w
                       + rb.x * br1.x + rb.y * br1.y + rb.z * br1.z + rb.w * br1.w;
                }
                s[j] += (double)d;
            }
        }
    }
    // ---- reduce over (kh, g) = lane bits 0..3
    #pragma unroll
    for (int m = 1; m < 16; m <<= 1) {
        #pragma unroll
        for (int j = 0; j < 4; ++j) s[j] += __shfl_xor(s[j], m, 64);
    }
    if ((t & 15) == 0) {
        float base = cB[eg];
        #pragma unroll
        for (int j = 0; j < 4; ++j)
            logits[n0 + e0 + j] = (float)s[j] + base;
    }
}

// ---------------------------------------------------------------------------
// Kernel 4: deterministic segment max + exp-sum (seg sorted -> contiguous runs)
// ---------------------------------------------------------------------------
__global__ void k_segstats(const int* __restrict__ edges, const float* __restrict__ logits,
                           float* __restrict__ smaxf, float* __restrict__ den)
{
    int n = blockIdx.x * 256 + threadIdx.x;
    if (n >= NN) return;
    int s = edges[(size_t)n * 8 + 6];
    if (n > 0 && edges[(size_t)(n - 1) * 8 + 6] == s) return;   // not a run start
    float m = -INFINITY;
    int k = n;
    while (k < NN && edges[(size_t)k * 8 + 6] == s) {
        m = fmaxf(m, logits[k]);
        ++k;
    }
    float d = 0.f;
    for (int q = n; q < k; ++q) d += expf(logits[q] - m);
    smaxf[s] = m;
    den[s]   = d;
}

// ---------------------------------------------------------------------------
// Kernel 5 v2: register bitonic sort (shfl for stride<64, LDS for >=64),
// descending stable by index. 64 blocks x 1024 threads.
// ---------------------------------------------------------------------------
__global__ void k_topk(const int* __restrict__ edges, const float* __restrict__ logits,
                       const float* __restrict__ smaxf, const float* __restrict__ den,
                       const float* __restrict__ score, float* __restrict__ out)
{
    __shared__ float vsh[1024];
    __shared__ int   ish[1024];
    const int r = blockIdx.x, t = threadIdx.x;
    const int n = r * 1024 + t;
    float v; int idx = t;
    {
        int s = edges[(size_t)n * 8 + 6];
        v = expf(logits[n] - smaxf[s]) / den[s] * score[s];
    }
    for (int size = 2; size <= 1024; size <<= 1) {
        for (int stride = size >> 1; stride > 0; stride >>= 1) {
            float v2; int i2;
            if (stride < 64) {
                v2 = __shfl_xor(v, stride, 64);
                i2 = __shfl_xor(idx, stride, 64);
            } else {
                __syncthreads();
                vsh[t] = v; ish[t] = idx;
                __syncthreads();
                v2 = vsh[t ^ stride]; i2 = ish[t ^ stride];
            }
            bool before = (v > v2) || (v == v2 && idx < i2);   // desc, stable
            bool desc   = ((t & size) == 0);
            bool keep   = ((t & stride) == 0) ? (before == desc) : (before != desc);
            if (!keep) { v = v2; idx = i2; }
        }
    }
    if (t < KTOP) {
        int orig = r * 1024 + idx;
        int ss   = edges[(size_t)orig * 8 + 6];
        float soft = expf(logits[orig] - smaxf[ss]) / den[ss];
        int o = r * KTOP + t;
        out[o]        = v;                       // pruned_target_score
        out[4096 + o] = soft;                    // pruned_softmax
        #pragma unroll
        for (int q = 0; q < 8; ++q)              // pruned_edges
            out[8192 + (size_t)o * 8 + q] = (float)edges[(size_t)orig * 8 + q];
        out[40960 + o] = (float)orig;            // orig_indices
    }
}

// ---------------------------------------------------------------------------
extern "C" void kernel_launch(void* const* d_in, const int* in_sizes, int n_in,
                              void* d_out, int out_size, void* d_ws, size_t ws_size,
                              hipStream_t stream)
{
    (void)in_sizes; (void)n_in; (void)out_size; (void)ws_size;
    const float* score = (const float*)d_in[0];
    const float* vnr   = (const float*)d_in[1];
    const float* rel   = (const float*)d_in[2];
    const float* qs    = (const float*)d_in[3];
    const float* qr    = (const float*)d_in[4];
    const float* Wq    = (const float*)d_in[5];
    const float* Wk    = (const float*)d_in[6];
    const int*   edges = (const int*)  d_in[7];
    float* out = (float*)d_out;

    float* ws     = (float*)d_ws;
    float* G      = ws;                 // 512*512
    float* bL     = G      + 262144;    // 64*256
    float* bR     = bL     + 16384;     // 64*256
    float* cB     = bR     + 16384;     // 64
    float* smaxf  = cB     + 64;        // 65536
    float* den    = smaxf  + 65536;     // 65536
    float* logits = den    + 65536;     // 65536

    k_gemm_G  <<<256, 256, 0, stream>>>(Wq, Wk, G);
    k_batch   <<<64, 256, 0, stream>>>(qs, qr, G, bL, bR, cB);
    k_edge    <<<1024, 256, 0, stream>>>(vnr, rel, edges, G, bL, bR, cB, logits);
    k_segstats<<<256, 256, 0, stream>>>(edges, logits, smaxf, den);
    k_topk    <<<64, 1024, 0, stream>>>(edges, logits, smaxf, den, score, out);
}

// Round 7
// 308.091 us; speedup vs baseline: 1.2887x; 1.2887x over previous
//
#include <hip/hip_runtime.h>
#include <math.h>

#define NN 65536   // edges
#define KTOP 64

typedef const __attribute__((address_space(1))) void* gas_ptr;
typedef __attribute__((address_space(3))) void* las_ptr;

__device__ __forceinline__ void gload_lds16(const float* g, float* lds) {
    __builtin_amdgcn_global_load_lds((gas_ptr)g, (las_ptr)lds, 16, 0, 0);
}

// ---------------------------------------------------------------------------
// Kernel 1: G = Wq^T @ Wk (512x512) -> linear G (for k_batch) and, for the
// Ghh quadrant (rows<256, cols<256), a pre-swizzled 8-tile image whose linear
// byte order equals k_edge's Bt LDS image (tile = (m>>7)*4 + (n>>6)).
// ---------------------------------------------------------------------------
__global__ void k_gemm_G(const float* __restrict__ Wq, const float* __restrict__ Wk,
                         float* __restrict__ G, float* __restrict__ Gimg)
{
    __shared__ float As[32][33];
    __shared__ float Bs[32][33];
    const int t  = threadIdx.x;
    const int tm = t >> 4, tn = t & 15;
    const int m0 = (blockIdx.x >> 4) * 32, n0 = (blockIdx.x & 15) * 32;
    float a00 = 0.f, a01 = 0.f, a10 = 0.f, a11 = 0.f;
    for (int d0 = 0; d0 < 512; d0 += 32) {
        for (int i = t; i < 1024; i += 256) {
            int r = i >> 5, c = i & 31;
            As[r][c] = Wq[(size_t)(d0 + r) * 512 + m0 + c];
            Bs[r][c] = Wk[(size_t)(d0 + r) * 512 + n0 + c];
        }
        __syncthreads();
        #pragma unroll 8
        for (int k = 0; k < 32; ++k) {
            float x0 = As[k][tm * 2], x1 = As[k][tm * 2 + 1];
            float y0 = Bs[k][tn * 2], y1 = Bs[k][tn * 2 + 1];
            a00 += x0 * y0; a01 += x0 * y1; a10 += x1 * y0; a11 += x1 * y1;
        }
        __syncthreads();
    }
    const int mA = m0 + tm * 2, nA = n0 + tn * 2;
    G[(size_t)(mA + 0) * 512 + nA + 0] = a00;
    G[(size_t)(mA + 0) * 512 + nA + 1] = a01;
    G[(size_t)(mA + 1) * 512 + nA + 0] = a10;
    G[(size_t)(mA + 1) * 512 + nA + 1] = a11;
    if (m0 < 256 && n0 < 256) {
        auto img = [&](int m, int n, float v) {
            int kk = m & 127, c = n & 63;
            int tile = ((m >> 7) << 2) | (n >> 6);
            int x = c ^ (((kk & 7) << 3) ^ (((kk >> 6) & 1) << 2));
            Gimg[tile * 8192 + kk * 64 + x] = v;
        };
        img(mA, nA, a00); img(mA, nA + 1, a01);
        img(mA + 1, nA, a10); img(mA + 1, nA + 1, a11);
    }
}

// ---------------------------------------------------------------------------
// Kernel 2: per-batch vectors bL, bR, cB (unchanged)
// ---------------------------------------------------------------------------
__global__ void k_batch(const float* __restrict__ qs, const float* __restrict__ qr,
                        const float* __restrict__ G,
                        float* __restrict__ bL, float* __restrict__ bR, float* __restrict__ cB)
{
    const int e = blockIdx.x, t = threadIdx.x;
    __shared__ float qcat[256];
    __shared__ float whi[256];
    __shared__ float red[256];
    qcat[t] = (t < 128) ? qs[(size_t)e * 128 + t] : qr[(size_t)e * 128 + (t - 128)];
    __syncthreads();
    float w0 = 0.f, w1 = 0.f;
    for (int r = 0; r < 256; ++r) {
        float q = qcat[r];
        w0 += G[(size_t)t * 512 + 256 + r] * q;
        w1 += G[(size_t)(t + 256) * 512 + 256 + r] * q;
    }
    bL[(size_t)e * 256 + t] = w0;
    whi[t] = w1;
    float v = 0.f;
    for (int r = 0; r < 256; ++r)
        v += qcat[r] * G[(size_t)(256 + r) * 512 + t];
    bR[(size_t)e * 256 + t] = v;
    __syncthreads();
    red[t] = qcat[t] * whi[t];
    __syncthreads();
    for (int s = 128; s > 0; s >>= 1) {
        if (t < s) red[t] += red[t + s];
        __syncthreads();
    }
    if (t == 0) cB[e] = red[0];
}

// ---------------------------------------------------------------------------
// Kernel 3 v3: per-edge logits. 64 edges/block, 256 threads.
// Thread (p=t>>4, g=(t>>1)&7, kh=t&1): 4 edges x 8 cols x k-half.
// Bt staged via global_load_lds from the pre-swizzled Gimg (0 VGPRs);
// At kt=1 rows loaded at the staging point (no cross-phase live range);
// only rpre (32 VGPR) is held across the FMA loop -> no spill.
// ---------------------------------------------------------------------------
#define FMAROW(J, AX) \
    acc[J][0] += AX * b0.x; acc[J][1] += AX * b0.y; \
    acc[J][2] += AX * b0.z; acc[J][3] += AX * b0.w; \
    acc[J][4] += AX * b1.x; acc[J][5] += AX * b1.y; \
    acc[J][6] += AX * b1.z; acc[J][7] += AX * b1.w;

__launch_bounds__(256, 2)
__global__ void k_edge(const float* __restrict__ vnr, const float* __restrict__ rel,
                       const int* __restrict__ edges, const float* __restrict__ Gimg,
                       const float* __restrict__ bL, const float* __restrict__ bR,
                       const float* __restrict__ cB, float* __restrict__ logits)
{
    __shared__ __align__(16) float At[128][64];
    __shared__ __align__(16) float Bt[128][64];
    __shared__ __align__(16) float bLs[256];
    __shared__ __align__(16) float bRs[256];
    __shared__ int jL[64];

    const int t  = threadIdx.x;
    const int n0 = blockIdx.x * 64;
    const int eg = n0 >> 10;

    const int kh = t & 1;
    const int g  = (t >> 1) & 7;
    const int p  = t >> 4;
    const int e0 = 4 * p;
    const int eS = t & 63, w = t >> 6;   // w = wave id (uniform per wave)
    float* BtF = &Bt[0][0];

    if (t < 64) jL[t] = edges[(size_t)(n0 + t) * 8 + 7];
    bLs[t] = bL[(size_t)eg * 256 + t];
    bRs[t] = bR[(size_t)eg * 256 + t];

    // ---- At (kt=0): gathered vnr[seg] rows -> transposed LDS store
    {
        int seg = edges[(size_t)(n0 + eS) * 8 + 6];
        const float* src = vnr + (size_t)seg * 128 + w * 32;
        float4 a[8];
        #pragma unroll
        for (int q = 0; q < 8; ++q) a[q] = *(const float4*)(src + q * 4);
        #pragma unroll
        for (int q = 0; q < 8; ++q) {
            int k = w * 32 + q * 4;
            At[k + 0][eS] = a[q].x; At[k + 1][eS] = a[q].y;
            At[k + 2][eS] = a[q].z; At[k + 3][eS] = a[q].w;
        }
    }
    __syncthreads();                       // At(kt0) + jL/bLs/bRs visible

    double s[4] = {0.0, 0.0, 0.0, 0.0};

    for (int kt = 0; kt < 2; ++kt) {
        if (kt == 1) {
            // restage At with rel rows; loads issued just before the barrier
            const float* src = rel + (size_t)(n0 + eS) * 128 + w * 32;
            float4 a[8];
            #pragma unroll
            for (int q = 0; q < 8; ++q) a[q] = *(const float4*)(src + q * 4);
            __syncthreads();               // all reads of At(kt0)/Bt(kt0,ct3) done
            #pragma unroll
            for (int q = 0; q < 8; ++q) {
                int k = w * 32 + q * 4;
                At[k + 0][eS] = a[q].x; At[k + 1][eS] = a[q].y;
                At[k + 2][eS] = a[q].z; At[k + 3][eS] = a[q].w;
            }
            __syncthreads();               // At(kt1) visible
        }
        // ---- bL partial: k = (t&15)*8 .. +7 for this thread's 4 edges
        {
            const int kb = (t & 15) * 8;
            float la[4] = {0.f, 0.f, 0.f, 0.f};
            #pragma unroll
            for (int i = 0; i < 8; ++i) {
                float bl = bLs[kt * 128 + kb + i];
                float4 a = *(const float4*)&At[kb + i][e0];
                la[0] += a.x * bl; la[1] += a.y * bl;
                la[2] += a.z * bl; la[3] += a.w * bl;
            }
            #pragma unroll
            for (int j = 0; j < 4; ++j) s[j] += (double)la[j];
        }

        for (int ct = 0; ct < 4; ++ct) {
            if (ct > 0) __syncthreads();   // previous Bt fully consumed
            // ---- async stage Bt tile direct-to-LDS from pre-swizzled image
            {
                const int tile = kt * 4 + ct;
                const float* gsrc = Gimg + tile * 8192 + w * 256 + (t & 63) * 4;
                float* ldst = BtF + w * 256;           // wave-uniform base
                #pragma unroll
                for (int r = 0; r < 8; ++r)
                    gload_lds16(gsrc + r * 1024, ldst + r * 1024);
            }
            // ---- epilogue Rh rows (complete by the drain at the next barrier)
            float4 rpre[8];
            #pragma unroll
            for (int j = 0; j < 4; ++j) {
                const float* rp = (ct < 2)
                    ? (vnr + (size_t)jL[e0 + j] * 128 + ct * 64 + g * 8)
                    : (rel + (size_t)(n0 + e0 + j) * 128 + (ct - 2) * 64 + g * 8);
                rpre[2 * j]     = *(const float4*)(rp);
                rpre[2 * j + 1] = *(const float4*)(rp + 4);
            }
            __syncthreads();               // Bt visible (vmcnt drain covers rpre too)
            // ---- 64(e) x 64(c) x 64(k-half) FMA tile
            float acc[4][8] = {};
            const int cb0 = (g * 8) ^ (kh << 2);
            #pragma unroll 8
            for (int i = 0; i < 64; ++i) {
                const int kk = kh * 64 + i;
                float4 a  = *(const float4*)&At[kk][e0];
                const int cb = cb0 ^ ((i & 7) << 3);
                float4 b0 = *(const float4*)&Bt[kk][cb];
                float4 b1 = *(const float4*)&Bt[kk][cb ^ 4];
                FMAROW(0, a.x) FMAROW(1, a.y) FMAROW(2, a.z) FMAROW(3, a.w)
            }
            // ---- epilogue: dot with Rh (+ bR term once: kt==0 && kh==0)
            const int cbase = ct * 64 + g * 8;
            const bool doBR = (kt == 0) && (kh == 0);
            float4 br0, br1;
            if (doBR) {
                br0 = *(const float4*)&bRs[cbase];
                br1 = *(const float4*)&bRs[cbase + 4];
            }
            #pragma unroll
            for (int j = 0; j < 4; ++j) {
                float4 ra = rpre[2 * j], rb = rpre[2 * j + 1];
                float d = acc[j][0] * ra.x + acc[j][1] * ra.y + acc[j][2] * ra.z + acc[j][3] * ra.w
                        + acc[j][4] * rb.x + acc[j][5] * rb.y + acc[j][6] * rb.z + acc[j][7] * rb.w;
                if (doBR) {
                    d += ra.x * br0.x + ra.y * br0.y + ra.z * br0.z + ra.w * br0.w
                       + rb.x * br1.x + rb.y * br1.y + rb.z * br1.z + rb.w * br1.w;
                }
                s[j] += (double)d;
            }
        }
    }
    // ---- reduce over (kh, g) = lane bits 0..3
    #pragma unroll
    for (int m = 1; m < 16; m <<= 1) {
        #pragma unroll
        for (int j = 0; j < 4; ++j) s[j] += __shfl_xor(s[j], m, 64);
    }
    if ((t & 15) == 0) {
        float base = cB[eg];
        #pragma unroll
        for (int j = 0; j < 4; ++j)
            logits[n0 + e0 + j] = (float)s[j] + base;
    }
}

// ---------------------------------------------------------------------------
// Kernel 4 v2: deterministic segment softmax, fused: run-start thread writes
// soft[] and tscore[] for its whole run (seg sorted -> contiguous runs).
// ---------------------------------------------------------------------------
__global__ void k_segstats(const int* __restrict__ edges, const float* __restrict__ logits,
                           const float* __restrict__ score,
                           float* __restrict__ soft, float* __restrict__ tsc)
{
    int n = blockIdx.x * 256 + threadIdx.x;
    if (n >= NN) return;
    int s = edges[(size_t)n * 8 + 6];
    if (n > 0 && edges[(size_t)(n - 1) * 8 + 6] == s) return;   // not a run start
    float m = -INFINITY;
    int k = n;
    while (k < NN && edges[(size_t)k * 8 + 6] == s) {
        m = fmaxf(m, logits[k]);
        ++k;
    }
    float d = 0.f;
    for (int q = n; q < k; ++q) d += expf(logits[q] - m);
    float sc = score[s];
    for (int q = n; q < k; ++q) {
        float so = expf(logits[q] - m) / d;
        soft[q] = so;
        tsc[q]  = so * sc;
    }
}

// ---------------------------------------------------------------------------
// Kernel 5 v3: register bitonic sort on tscore (shfl <64, LDS >=64),
// descending stable by index. 64 blocks x 1024 threads.
// ---------------------------------------------------------------------------
__global__ void k_topk(const int* __restrict__ edges, const float* __restrict__ soft,
                       const float* __restrict__ tsc, float* __restrict__ out)
{
    __shared__ float vsh[1024];
    __shared__ int   ish[1024];
    const int r = blockIdx.x, t = threadIdx.x;
    const int n = r * 1024 + t;
    float v = tsc[n];
    int idx = t;
    for (int size = 2; size <= 1024; size <<= 1) {
        for (int stride = size >> 1; stride > 0; stride >>= 1) {
            float v2; int i2;
            if (stride < 64) {
                v2 = __shfl_xor(v, stride, 64);
                i2 = __shfl_xor(idx, stride, 64);
            } else {
                __syncthreads();
                vsh[t] = v; ish[t] = idx;
                __syncthreads();
                v2 = vsh[t ^ stride]; i2 = ish[t ^ stride];
            }
            bool before = (v > v2) || (v == v2 && idx < i2);   // desc, stable
            bool desc   = ((t & size) == 0);
            bool keep   = ((t & stride) == 0) ? (before == desc) : (before != desc);
            if (!keep) { v = v2; idx = i2; }
        }
    }
    if (t < KTOP) {
        int orig = r * 1024 + idx;
        int o = r * KTOP + t;
        out[o]        = v;                       // pruned_target_score
        out[4096 + o] = soft[orig];              // pruned_softmax
        #pragma unroll
        for (int q = 0; q < 8; ++q)              // pruned_edges
            out[8192 + (size_t)o * 8 + q] = (float)edges[(size_t)orig * 8 + q];
        out[40960 + o] = (float)orig;            // orig_indices
    }
}

// ---------------------------------------------------------------------------
extern "C" void kernel_launch(void* const* d_in, const int* in_sizes, int n_in,
                              void* d_out, int out_size, void* d_ws, size_t ws_size,
                              hipStream_t stream)
{
    (void)in_sizes; (void)n_in; (void)out_size; (void)ws_size;
    const float* score = (const float*)d_in[0];
    const float* vnr   = (const float*)d_in[1];
    const float* rel   = (const float*)d_in[2];
    const float* qs    = (const float*)d_in[3];
    const float* qr    = (const float*)d_in[4];
    const float* Wq    = (const float*)d_in[5];
    const float* Wk    = (const float*)d_in[6];
    const int*   edges = (const int*)  d_in[7];
    float* out = (float*)d_out;

    float* ws     = (float*)d_ws;
    float* G      = ws;                 // 512*512          = 262144
    float* Gimg   = G      + 262144;    // 8*8192           = 65536
    float* bL     = Gimg   + 65536;     // 64*256
    float* bR     = bL     + 16384;     // 64*256
    float* cB     = bR     + 16384;     // 64
    float* logits = cB     + 64;        // 65536
    float* soft   = logits + 65536;     // 65536
    float* tsc    = soft   + 65536;     // 65536

    k_gemm_G  <<<256, 256, 0, stream>>>(Wq, Wk, G, Gimg);
    k_batch   <<<64, 256, 0, stream>>>(qs, qr, G, bL, bR, cB);
    k_edge    <<<1024, 256, 0, stream>>>(vnr, rel, edges, Gimg, bL, bR, cB, logits);
    k_segstats<<<256, 256, 0, stream>>>(edges, logits, score, soft, tsc);
    k_topk    <<<64, 1024, 0, stream>>>(edges, soft, tsc, out);
}